// Round 1
// baseline (439.672 us; speedup 1.0000x reference)
//
#include <hip/hip_runtime.h>

// Problem constants
#define BB 8
#define PP 5000
#define DD 64
#define NBP (BB * PP)        // 40000 pairs
#define NPOSC 20000
#define SLOTS 16             // direct-slot inverse index width; overflow handled in main
#define GRID_POS (NPOSC / 4) // 5000 blocks x 4 waves = one wave per position

typedef float v4f __attribute__((ext_vector_type(4)));

// ---------------------------------------------------------------------------
// Prep: atomically claim a slot in the per-position list (no hist, no scan).
// 2 pairs per thread, int2 position loads. Overflow -> global list.
__global__ __launch_bounds__(256) void claim_kernel(
    const int* __restrict__ positions,
    int* __restrict__ cnt,        // [NPOSC] zeroed
    int* __restrict__ ovf_cnt,    // [1] zeroed
    int* __restrict__ order2,     // [NPOSC * SLOTS]
    int* __restrict__ ovf)        // [NBP]
{
    const int tid  = blockIdx.x * 256 + threadIdx.x;
    const int base = tid * 2;
    if (base >= NBP) return;
    const int2 p2 = ((const int2*)positions)[tid];
    {
        const int k = atomicAdd(&cnt[p2.x], 1);
        if (k < SLOTS) order2[p2.x * SLOTS + k] = base;
        else           ovf[atomicAdd(ovf_cnt, 1)] = base;
    }
    {
        const int k = atomicAdd(&cnt[p2.y], 1);
        if (k < SLOTS) order2[p2.y * SLOTS + k] = base + 1;
        else           ovf[atomicAdd(ovf_cnt, 1)] = base + 1;
    }
}

// ---------------------------------------------------------------------------
// One chunk of M pairs sharing a single kernel-row sweep.
// NOTE: krow loads are PLAIN (cached) now — each row is read once per
// iteration, so the only possible cache benefit is cross-iteration L3
// residency, which the nt (evict-first) hint was defeating.
// Output stores stay nontemporal (write-once, never re-read by us).
template<int M>
__device__ __forceinline__ void pos_chunk(
    const int* __restrict__ slot, int c,
    const int2* __restrict__ all2,
    const float* __restrict__ allele_table,
    const v4f* __restrict__ krow,
    const v4f bv, const int lane, const int dg,
    v4f* __restrict__ out4)
{
    int   bp[M];
    float a[M];
    v4f   acc[M];
#pragma unroll
    for (int j = 0; j < M; ++j) {
        bp[j] = slot[c + j];
        const int2 e = all2[bp[j]];
        a[j] = allele_table[e.x * DD + lane] + allele_table[e.y * DD + lane];
        acc[j] = (v4f)(0.f);
    }
#pragma unroll
    for (int i = 0; i < 16; ++i) {
        const int d = i * 4 + dg;
        const v4f kv = krow[i * 64 + lane];
#pragma unroll
        for (int j = 0; j < M; ++j)
            acc[j] += __shfl(a[j], d, 64) * kv;
    }
#pragma unroll
    for (int j = 0; j < M; ++j) {
#pragma unroll
        for (int off = 16; off <= 32; off <<= 1) {
            acc[j].x += __shfl_xor(acc[j].x, off, 64);
            acc[j].y += __shfl_xor(acc[j].y, off, 64);
            acc[j].z += __shfl_xor(acc[j].z, off, 64);
            acc[j].w += __shfl_xor(acc[j].w, off, 64);
        }
    }
    if (lane < 16) {
#pragma unroll
        for (int j = 0; j < M; ++j)
            __builtin_nontemporal_store(acc[j] + bv,
                                        &out4[(size_t)bp[j] * (DD / 4) + lane]);
    }
}

// ---------------------------------------------------------------------------
// Main: one 64-lane wave per POSITION, ascending position order per XCD
// (5000 = 8 x 625 swizzle) -> each XCD streams a contiguous ~41 MB slab of
// kernel_table; each needed 16 KB row fetched exactly once (algorithmic
// dedup). Overflow pairs (count > SLOTS, normally zero) are drained by
// blocks 0..15 at the end — tail kernel is fused away.
__global__ __launch_bounds__(256) void allele_embed_kernel(
    const int2* __restrict__ all2,          // [NBP] (ploidy pair packed)
    const int* __restrict__ positions,      // [NBP]
    const float* __restrict__ allele_table, // [16, 64]
    const v4f* __restrict__ ktab4,          // [NPOSC * 1024]
    const v4f* __restrict__ btab4,          // [NPOSC * 16]
    const int* __restrict__ cnt,            // [NPOSC]
    const int* __restrict__ order2,         // [NPOSC * SLOTS]
    const int* __restrict__ ovf_cnt,        // [1]
    const int* __restrict__ ovf,            // [NBP]
    v4f* __restrict__ out4)                 // [NBP * 16]
{
    const int wave = threadIdx.x >> 6;
    const int lane = threadIdx.x & 63;
    const int dg   = lane >> 4;             // d-group 0..3
    const int work = (blockIdx.x & 7) * (GRID_POS / 8) + (blockIdx.x >> 3);
    const int pos  = work * 4 + wave;

    int n = cnt[pos];
    if (n > SLOTS) n = SLOTS;               // overflow handled below
    if (n > 0) {
        const v4f* __restrict__ krow = ktab4 + (size_t)pos * (DD * DD / 4);
        const int* __restrict__ slot = order2 + pos * SLOTS;
        const v4f bv = btab4[(size_t)pos * (DD / 4) + (lane & 15)];

        int c = 0;
        for (; n - c >= 4; c += 4)
            pos_chunk<4>(slot, c, all2, allele_table, krow, bv, lane, dg, out4);
        const int m = n - c;
        if      (m == 1) pos_chunk<1>(slot, c, all2, allele_table, krow, bv, lane, dg, out4);
        else if (m == 2) pos_chunk<2>(slot, c, all2, allele_table, krow, bv, lane, dg, out4);
        else if (m == 3) pos_chunk<3>(slot, c, all2, allele_table, krow, bv, lane, dg, out4);
    }

    // Fused tail: overflow pairs (normally ZERO) drained by blocks 0..15.
    if (blockIdx.x < 16) {
        const int nov = *ovf_cnt;
        for (int i = blockIdx.x * 4 + wave; i < nov; i += 64) {
            const int bp  = ovf[i];
            const int p   = positions[bp];
            const int2 al = all2[bp];
            const float a = allele_table[al.x * DD + lane]
                          + allele_table[al.y * DD + lane];
            const v4f* __restrict__ krow = ktab4 + (size_t)p * (DD * DD / 4);
            v4f acc = (v4f)(0.f);
#pragma unroll
            for (int k = 0; k < 16; ++k) {
                const float ad = __shfl(a, k * 4 + dg, 64);
                acc += ad * krow[k * 64 + lane];
            }
#pragma unroll
            for (int off = 16; off <= 32; off <<= 1) {
                acc.x += __shfl_xor(acc.x, off, 64); acc.y += __shfl_xor(acc.y, off, 64);
                acc.z += __shfl_xor(acc.z, off, 64); acc.w += __shfl_xor(acc.w, off, 64);
            }
            if (lane < 16) {
                const v4f bv = btab4[(size_t)p * (DD / 4) + (lane & 15)];
                __builtin_nontemporal_store(acc + bv,
                                            &out4[(size_t)bp * (DD / 4) + lane]);
            }
        }
    }
}

extern "C" void kernel_launch(void* const* d_in, const int* in_sizes, int n_in,
                              void* d_out, int out_size, void* d_ws, size_t ws_size,
                              hipStream_t stream) {
    const int*   alleles      = (const int*)d_in[0];
    const int*   positions    = (const int*)d_in[1];
    const float* allele_table = (const float*)d_in[2];
    const v4f*   ktab4        = (const v4f*)d_in[3];
    const v4f*   btab4        = (const v4f*)d_in[4];
    v4f* out4                 = (v4f*)d_out;
    const int2* all2          = (const int2*)alleles;

    // ws layout (ints): cnt[20000] | ovf_cnt[1] (+pad to 32) | order2[20000*16] | ovf[40000]
    int* cnt     = (int*)d_ws;
    int* ovf_cnt = cnt + NPOSC;
    int* order2  = cnt + NPOSC + 32;
    int* ovf     = order2 + NPOSC * SLOTS;

    hipMemsetAsync(cnt, 0, (NPOSC + 32) * sizeof(int), stream);

    const int gclaim = (NBP / 2 + 255) / 256;
    claim_kernel<<<gclaim, 256, 0, stream>>>(positions, cnt, ovf_cnt, order2, ovf);

    allele_embed_kernel<<<GRID_POS, 256, 0, stream>>>(
        all2, positions, allele_table, ktab4, btab4, cnt, order2, ovf_cnt, ovf, out4);
}